// Round 4
// baseline (1990.023 us; speedup 1.0000x reference)
//
#include <hip/hip_runtime.h>
#include <stdint.h>

// Problem constants
#define BATCH 128
#define LFULL 4096
#define TT 48            // number of tags
#define NPOT 4094        // pot timesteps (L-2)
#define NBP  4093        // number of bp entries / stored state vectors
#define SEG  64          // backtrack segment length
#define NSEG 64          // ceil(NBP/SEG)
#define SLOT 192         // bytes per state slot (48 floats)

// ---------------------------------------------------------------------------
// Exact max over 48 floats (order-independent for exact value). max3-friendly.
__device__ __forceinline__ float maxtree48(const float* s) {
    float r[16];
#pragma unroll
    for (int j = 0; j < 16; ++j)
        r[j] = fmaxf(fmaxf(s[3*j], s[3*j+1]), s[3*j+2]);
#pragma unroll
    for (int j = 0; j < 8; ++j) r[j] = fmaxf(r[j], r[j+8]);
#pragma unroll
    for (int j = 0; j < 4; ++j) r[j] = fmaxf(r[j], r[j+4]);
    return fmaxf(fmaxf(r[0], r[1]), fmaxf(r[2], r[3]));
}

// ---------------------------------------------------------------------------
// K1: forward Viterbi scan (values only, no argmax). ONE WAVE handles TWO
// batches (chains A and B), alternating step-sections so each chain's LDS
// write->read round-trip latency hides under the other chain's VALU work.
// Single wave per block: no block barrier in the loop; LDS ops from one wave
// complete in order (lgkmcnt), wave_barrier pins source order.
// Stores state vectors s_0..s_4092 into the pot region of d_out (scratch).
// Also writes last_tag (byte) into bound[b][NSEG].
__global__ __launch_bounds__(64) void k_forward(const float* __restrict__ in,
                                                const float* __restrict__ trans,
                                                char* __restrict__ statesBase,
                                                unsigned char* __restrict__ bound) {
    const int lane = threadIdx.x;
    const int kk = (lane < TT) ? lane : 0;
    const int bA = blockIdx.x * 2;
    const int bB = bA + 1;

    __shared__ float ldsT[TT * TT];
    __shared__ __align__(16) float lsA[TT];
    __shared__ __align__(16) float lsB[TT];

    for (int i = lane; i < TT * TT; i += 64) ldsT[i] = trans[i];
    __syncthreads();

    float tcol[TT];                       // column kk of T, shared by chains
#pragma unroll
    for (int j = 0; j < TT; ++j) tcol[j] = ldsT[j * TT + kk];

    const float* inA = in + (size_t)bA * (LFULL * TT);
    const float* inB = in + (size_t)bB * (LFULL * TT);
    char* sA = statesBase + (size_t)bA * NBP * SLOT;
    char* sB = statesBase + (size_t)bB * NBP * SLOT;

    // s0 = pot[b,0,:] = in[b,1,:] -> LDS buffers + slot 0
    {
        float s0 = inA[TT + kk];
        if (lane < TT) { lsA[lane] = s0; ((float*)sA)[lane] = s0; }
        s0 = inB[TT + kk];
        if (lane < TT) { lsB[lane] = s0; ((float*)sB)[lane] = s0; }
    }
    __builtin_amdgcn_wave_barrier();

    // one step-section for one chain:
    //   read 48 state floats (12 x b128, streamed into add/max3 tree),
    //   snew = max + e, overwrite LDS buffer, store snapshot to global.
    auto STEP = [&](float* __restrict__ ls, char* __restrict__ sb, int t, float e) {
        float cand[TT];
#pragma unroll
        for (int j = 0; j < TT; j += 4) {
            float4 v = *(const float4*)(&ls[j]);
            cand[j]   = v.x + tcol[j];
            cand[j+1] = v.y + tcol[j+1];
            cand[j+2] = v.z + tcol[j+2];
            cand[j+3] = v.w + tcol[j+3];
        }
        float snew = maxtree48(cand) + e;
        __builtin_amdgcn_wave_barrier();          // reads before overwrite
        if (lane < TT) {
            ls[lane] = snew;
            if (t <= NBP - 1)
                *(float*)(sb + (size_t)t * SLOT + (size_t)lane * 4) = snew;
        }
        __builtin_amdgcn_wave_barrier();          // write before next section
    };

    // emission for step t is pot[b,t,:] = in[b,t+1,:]
    auto LDA = [&](int t) -> float {
        return (t <= NBP) ? inA[(size_t)(t + 1) * TT + kk] : 0.0f;
    };
    auto LDB = [&](int t) -> float {
        return (t <= NBP) ? inB[(size_t)(t + 1) * TT + kk] : 0.0f;
    };

    float a0 = LDA(1), a1 = LDA(2), a2 = LDA(3), a3 = LDA(4);
    float b0 = LDB(1), b1 = LDB(2), b2 = LDB(3), b3 = LDB(4);
    int t = 1;
    for (; t + 3 <= NBP; t += 4) {
        STEP(lsA, sA, t,     a0); a0 = LDA(t + 4);
        STEP(lsB, sB, t,     b0); b0 = LDB(t + 4);
        STEP(lsA, sA, t + 1, a1); a1 = LDA(t + 5);
        STEP(lsB, sB, t + 1, b1); b1 = LDB(t + 5);
        STEP(lsA, sA, t + 2, a2); a2 = LDA(t + 6);
        STEP(lsB, sB, t + 2, b2); b2 = LDB(t + 6);
        STEP(lsA, sA, t + 3, a3); a3 = LDA(t + 7);
        STEP(lsB, sB, t + 3, b3); b3 = LDB(t + 7);
    }
    for (; t <= NBP; ++t) {
        STEP(lsA, sA, t, a0); a0 = a1; a1 = a2; a2 = a3;
        STEP(lsB, sB, t, b0); b0 = b1; b1 = b2; b2 = b3;
    }

    // last_tag = first-index argmax of final states (read back from LDS)
    if (lane == 0) {
        float best = lsA[0]; int bi = 0;
#pragma unroll
        for (int j = 1; j < TT; ++j)
            if (lsA[j] > best) { best = lsA[j]; bi = j; }
        bound[bA * (NSEG + 1) + NSEG] = (unsigned char)bi;
        best = lsB[0]; bi = 0;
#pragma unroll
        for (int j = 1; j < TT; ++j)
            if (lsB[j] > best) { best = lsB[j]; bi = j; }
        bound[bB * (NSEG + 1) + NSEG] = (unsigned char)bi;
    }
}

// ---------------------------------------------------------------------------
// K2: recompute backpointers bp_i[k] = argmax_j(s_i[j] + T[j][k]) for ALL
// (b,i,k), massively parallel. One wave per (b, chunk of 16 i's). bp bytes
// overwrite the first 48 bytes of each state slot (slot owned by this wave,
// fully read before written).
#define CHUNK 16
__global__ __launch_bounds__(256) void k_bp(const float* __restrict__ trans,
                                            char* __restrict__ statesBase) {
    const int lane = threadIdx.x & 63;
    const int wv = threadIdx.x >> 6;
    const int b = blockIdx.y * 4 + wv;
    const int i0 = blockIdx.x * CHUNK;
    const int kk = (lane < TT) ? lane : 0;

    __shared__ float ldsT[TT * TT];
    for (int i = threadIdx.x; i < TT * TT; i += 256) ldsT[i] = trans[i];
    __syncthreads();

    float tcol[TT];
#pragma unroll
    for (int j = 0; j < TT; ++j) tcol[j] = ldsT[j * TT + kk];

    char* sb = statesBase + (size_t)b * NBP * SLOT;

    for (int ii = 0; ii < CHUNK; ++ii) {
        int i = i0 + ii;
        if (i >= NBP) break;                     // uniform across wave
        const float* sp = (const float*)(sb + (size_t)i * SLOT);
        float sv[TT];
#pragma unroll
        for (int j = 0; j < TT; j += 4) {
            float4 v = *(const float4*)(sp + j);
            sv[j] = v.x; sv[j+1] = v.y; sv[j+2] = v.z; sv[j+3] = v.w;
        }
        float best = sv[0] + tcol[0]; int bi = 0;
#pragma unroll
        for (int j = 1; j < TT; ++j) {
            float v = sv[j] + tcol[j];
            if (v > best) { best = v; bi = j; }  // strict > : first-index wins
        }
        if (lane < TT)
            *(unsigned char*)(sb + (size_t)i * SLOT + lane) = (unsigned char)bi;
    }
}

// ---------------------------------------------------------------------------
// K3: compose each 64-step segment of backpointer maps into one map G_s
// (tag at segment end -> tag at segment start). Lane x traces start value x.
__global__ __launch_bounds__(64) void k_compose(const char* __restrict__ statesBase,
                                                unsigned char* __restrict__ G) {
    const int s = blockIdx.x, b = blockIdx.y;
    const int i0 = s * SEG;
    const int cnt = (SEG < NBP - i0) ? SEG : (NBP - i0);
    const int lane = threadIdx.x;

    __shared__ unsigned char lbp[SEG * TT];
    const char* sb = statesBase + (size_t)b * NBP * SLOT;
    for (int ii = 0; ii < cnt; ++ii) {
        if (lane < 12)
            ((uint32_t*)lbp)[ii * 12 + lane] =
                *(const uint32_t*)(sb + (size_t)(i0 + ii) * SLOT + (size_t)lane * 4);
    }
    __syncthreads();

    if (lane < TT) {
        int M = lane;
        for (int ii = cnt - 1; ii >= 0; --ii) M = lbp[ii * TT + M];
        G[(b * NSEG + s) * TT + lane] = (unsigned char)M;
    }
}

// ---------------------------------------------------------------------------
// K4: chain across segments: boundary tag at each segment start.
__global__ void k_boundary(const unsigned char* __restrict__ G,
                           unsigned char* __restrict__ bound) {
    int b = threadIdx.x;                 // 128 threads, 1 block
    int x = bound[b * (NSEG + 1) + NSEG];
    for (int s = NSEG - 1; s >= 0; --s) {
        x = G[(b * NSEG + s) * TT + x];
        bound[b * (NSEG + 1) + s] = x;
    }
}

// ---------------------------------------------------------------------------
// K5: fill tags within each segment by re-walking its bp maps from the known
// entering boundary tag. Writes final float tags.
__global__ __launch_bounds__(64) void k_fill(const char* __restrict__ statesBase,
                                             const unsigned char* __restrict__ bound,
                                             float* __restrict__ tags) {
    const int s = blockIdx.x, b = blockIdx.y;
    const int i0 = s * SEG;
    const int cnt = (SEG < NBP - i0) ? SEG : (NBP - i0);
    const int lane = threadIdx.x;

    __shared__ unsigned char lbp[SEG * TT];
    const char* sb = statesBase + (size_t)b * NBP * SLOT;
    for (int ii = 0; ii < cnt; ++ii) {
        if (lane < 12)
            ((uint32_t*)lbp)[ii * 12 + lane] =
                *(const uint32_t*)(sb + (size_t)(i0 + ii) * SLOT + (size_t)lane * 4);
    }
    __syncthreads();

    if (lane == 0) {
        int x = bound[b * (NSEG + 1) + s + 1];   // tag at position (s+1)*SEG (or last_tag)
        if (s == NSEG - 1)
            tags[(size_t)b * NPOT + (NPOT - 1)] = (float)x;
        for (int ii = cnt - 1; ii >= 0; --ii) {
            x = lbp[ii * TT + x];
            tags[(size_t)b * NPOT + i0 + ii] = (float)x;
        }
    }
}

// ---------------------------------------------------------------------------
// K6: final copies — pot = in[:,1:-1,:] and transitions passthrough.
__global__ __launch_bounds__(256) void k_copy(const float* __restrict__ in,
                                              const float* __restrict__ trans,
                                              float* __restrict__ out) {
    const int potN4 = (BATCH * NPOT * TT) / 4;   // 6,288,384 float4s
    const int rowN = NPOT * TT;                  // 196,512
    int idx = blockIdx.x * 256 + threadIdx.x;
    if (idx < potN4) {
        int p4 = idx * 4;
        int b = p4 / rowN;
        int off = p4 - b * rowN;
        float4 v = *(const float4*)(in + (size_t)b * (LFULL * TT) + off + TT);
        *(float4*)(out + p4) = v;
    } else if (idx < potN4 + (TT * TT) / 4) {
        int q = idx - potN4;
        *(float4*)(out + (size_t)BATCH * NPOT * TT + (size_t)q * 4) =
            *(const float4*)(trans + (size_t)q * 4);
    }
}

// ---------------------------------------------------------------------------
extern "C" void kernel_launch(void* const* d_in, const int* in_sizes, int n_in,
                              void* d_out, int out_size, void* d_ws, size_t ws_size,
                              hipStream_t stream) {
    (void)in_sizes; (void)n_in; (void)d_ws; (void)ws_size; (void)out_size;

    const float* in = (const float*)d_in[0];
    const float* trans = (const float*)d_in[1];
    float* out = (float*)d_out;

    // Scratch carved out of d_out (stream-ordered so everything is rewritten):
    //  - pot region   [0 .. 100.6MB): state vectors, then bp bytes in-place
    //  - trans region [2304 floats]: boundary tags (128 x 65 bytes)
    //  - tags region  [524032 floats]: segment maps G, then final tags
    char* statesBase = (char*)d_out;
    unsigned char* bound = (unsigned char*)(out + (size_t)BATCH * NPOT * TT);
    unsigned char* G = (unsigned char*)(out + (size_t)BATCH * NPOT * TT + TT * TT);
    float* tags = out + (size_t)BATCH * NPOT * TT + TT * TT;

    k_forward <<<dim3(BATCH / 2),    dim3(64),  0, stream>>>(in, trans, statesBase, bound);
    k_bp      <<<dim3(256, 32),      dim3(256), 0, stream>>>(trans, statesBase);
    k_compose <<<dim3(NSEG, BATCH),  dim3(64),  0, stream>>>(statesBase, G);
    k_boundary<<<dim3(1),            dim3(BATCH), 0, stream>>>(G, bound);
    k_fill    <<<dim3(NSEG, BATCH),  dim3(64),  0, stream>>>(statesBase, bound, tags);

    int total4 = (BATCH * NPOT * TT) / 4 + (TT * TT) / 4;
    k_copy    <<<dim3((total4 + 255) / 256), dim3(256), 0, stream>>>(in, trans, out);
}

// Round 5
// 1415.390 us; speedup vs baseline: 1.4060x; 1.4060x over previous
//
#include <hip/hip_runtime.h>
#include <stdint.h>

// Problem constants
#define BATCH 128
#define LFULL 4096
#define TT 48            // number of tags
#define NPOT 4094        // pot timesteps (L-2)
#define NBP  4093        // number of bp entries / stored state vectors
#define SEG  64          // backtrack segment length
#define NSEG 64          // ceil(NBP/SEG)
#define SLOT 192         // bytes per state slot (48 floats)

// ---------------------------------------------------------------------------
// Exact max over 48 floats (order-independent for exact value). max3-friendly.
__device__ __forceinline__ float maxtree48(const float* s) {
    float r[16];
#pragma unroll
    for (int j = 0; j < 16; ++j)
        r[j] = fmaxf(fmaxf(s[3*j], s[3*j+1]), s[3*j+2]);
#pragma unroll
    for (int j = 0; j < 8; ++j) r[j] = fmaxf(r[j], r[j+8]);
#pragma unroll
    for (int j = 0; j < 4; ++j) r[j] = fmaxf(r[j], r[j+4]);
    return fmaxf(fmaxf(r[0], r[1]), fmaxf(r[2], r[3]));
}

// ---------------------------------------------------------------------------
// K1: forward Viterbi scan (values only, no argmax). One wave per batch,
// one wave per block (128 blocks -> ~1 wave/SIMD on 128 CUs).
// KEY FIXES vs earlier rounds:
//  - __launch_bounds__(64, 1): VGPR budget up to 512 so tcol[48] stays
//    RESIDENT in registers (R0's 56-VGPR compile re-read T from LDS every
//    step, doubling LDS traffic on the serial chain).
//  - No __syncthreads in the loop (its vmcnt(0) drain exposed the snapshot
//    stores + killed the emission prefetch). Single-wave LDS ping buffer is
//    ordered by the in-order per-wave LDS queue; wave_barrier pins the
//    compiler's schedule. T is read straight from global (coalesced) once.
// Stores state vectors s_0..s_4092 into the pot region of d_out (scratch).
// Also writes last_tag (byte) into bound[b][NSEG].
__global__ __launch_bounds__(64, 1) void k_forward(const float* __restrict__ in,
                                                   const float* __restrict__ trans,
                                                   char* __restrict__ statesBase,
                                                   unsigned char* __restrict__ bound) {
    const int b = blockIdx.x;
    const int lane = threadIdx.x;
    const int kk = (lane < TT) ? lane : 0;

    __shared__ __align__(16) float lsw[64];   // state ping buffer (48 used)

    // tcol[j] = T[j][kk] — column kk resident in 48 VGPRs.
    // For fixed j, lanes read consecutive addresses -> coalesced.
    float tcol[TT];
#pragma unroll
    for (int j = 0; j < TT; ++j) tcol[j] = trans[j * TT + kk];

    const float* inb = in + (size_t)b * (LFULL * TT);
    char* sb = statesBase + (size_t)b * NBP * SLOT;

    // s0 = pot[b,0,:] = in[b,1,:]
    float s0 = inb[TT + kk];
    lsw[lane] = s0;                            // lanes 48-63 write junk, never read
    if (lane < TT) ((float*)sb)[lane] = s0;    // store s_0 (slot 0)
    __builtin_amdgcn_wave_barrier();

    // one Viterbi step: snew[k] = max_j(s[j]+T[j][k]) + e
    auto STEP = [&](int t, float e) {
        float cand[TT];
#pragma unroll
        for (int j = 0; j < TT; j += 4) {
            float4 v = *(const float4*)(&lsw[j]);
            cand[j]   = v.x + tcol[j];
            cand[j+1] = v.y + tcol[j+1];
            cand[j+2] = v.z + tcol[j+2];
            cand[j+3] = v.w + tcol[j+3];
        }
        float snew = maxtree48(cand) + e;
        __builtin_amdgcn_wave_barrier();       // all reads done before overwrite
        lsw[lane] = snew;                      // unconditional: no exec-mask dance
        __builtin_amdgcn_wave_barrier();       // write ordered before next reads
        if (t <= NBP - 1 && lane < TT)         // snapshot s_t (fire-and-forget)
            *(float*)(sb + (size_t)t * SLOT + (size_t)lane * 4) = snew;
    };

    // emission for step t is pot[b,t,:] = in[b,t+1,:]
    auto LD = [&](int t) -> float {
        return (t <= NBP) ? inb[(size_t)(t + 1) * TT + kk] : 0.0f;
    };

    float e0 = LD(1), e1 = LD(2), e2 = LD(3), e3 = LD(4);
    float e4 = LD(5), e5 = LD(6), e6 = LD(7), e7 = LD(8);
    int t = 1;
    for (; t + 7 <= NBP; t += 8) {
        STEP(t,     e0); e0 = LD(t + 8);
        STEP(t + 1, e1); e1 = LD(t + 9);
        STEP(t + 2, e2); e2 = LD(t + 10);
        STEP(t + 3, e3); e3 = LD(t + 11);
        STEP(t + 4, e4); e4 = LD(t + 12);
        STEP(t + 5, e5); e5 = LD(t + 13);
        STEP(t + 6, e6); e6 = LD(t + 14);
        STEP(t + 7, e7); e7 = LD(t + 15);
    }
    for (; t <= NBP; ++t) {
        STEP(t, e0);
        e0 = e1; e1 = e2; e2 = e3; e3 = e4; e4 = e5; e5 = e6; e6 = e7;
    }

    // last_tag = first-index argmax of final state (read once from LDS)
    if (lane == 0) {
        float best = lsw[0]; int bi = 0;
#pragma unroll
        for (int j = 1; j < TT; ++j) {
            float v = lsw[j];
            if (v > best) { best = v; bi = j; }
        }
        bound[b * (NSEG + 1) + NSEG] = (unsigned char)bi;
    }
}

// ---------------------------------------------------------------------------
// K2: recompute backpointers bp_i[k] = argmax_j(s_i[j] + T[j][k]) for ALL
// (b,i,k), massively parallel. One wave per (b, chunk of 16 i's). bp bytes
// overwrite the first 48 bytes of each state slot (slot owned by this wave,
// fully read before written).
#define CHUNK 16
__global__ __launch_bounds__(256) void k_bp(const float* __restrict__ trans,
                                            char* __restrict__ statesBase) {
    const int lane = threadIdx.x & 63;
    const int wv = threadIdx.x >> 6;
    const int b = blockIdx.y * 4 + wv;
    const int i0 = blockIdx.x * CHUNK;
    const int kk = (lane < TT) ? lane : 0;

    __shared__ float ldsT[TT * TT];
    for (int i = threadIdx.x; i < TT * TT; i += 256) ldsT[i] = trans[i];
    __syncthreads();

    float tcol[TT];
#pragma unroll
    for (int j = 0; j < TT; ++j) tcol[j] = ldsT[j * TT + kk];

    char* sb = statesBase + (size_t)b * NBP * SLOT;

    for (int ii = 0; ii < CHUNK; ++ii) {
        int i = i0 + ii;
        if (i >= NBP) break;                     // uniform across wave
        const float* sp = (const float*)(sb + (size_t)i * SLOT);
        float sv[TT];
#pragma unroll
        for (int j = 0; j < TT; j += 4) {
            float4 v = *(const float4*)(sp + j);
            sv[j] = v.x; sv[j+1] = v.y; sv[j+2] = v.z; sv[j+3] = v.w;
        }
        float best = sv[0] + tcol[0]; int bi = 0;
#pragma unroll
        for (int j = 1; j < TT; ++j) {
            float v = sv[j] + tcol[j];
            if (v > best) { best = v; bi = j; }  // strict > : first-index wins
        }
        if (lane < TT)
            *(unsigned char*)(sb + (size_t)i * SLOT + lane) = (unsigned char)bi;
    }
}

// ---------------------------------------------------------------------------
// K3: compose each 64-step segment of backpointer maps into one map G_s
// (tag at segment end -> tag at segment start). Lane x traces start value x.
__global__ __launch_bounds__(64) void k_compose(const char* __restrict__ statesBase,
                                                unsigned char* __restrict__ G) {
    const int s = blockIdx.x, b = blockIdx.y;
    const int i0 = s * SEG;
    const int cnt = (SEG < NBP - i0) ? SEG : (NBP - i0);
    const int lane = threadIdx.x;

    __shared__ unsigned char lbp[SEG * TT];
    const char* sb = statesBase + (size_t)b * NBP * SLOT;
    for (int ii = 0; ii < cnt; ++ii) {
        if (lane < 12)
            ((uint32_t*)lbp)[ii * 12 + lane] =
                *(const uint32_t*)(sb + (size_t)(i0 + ii) * SLOT + (size_t)lane * 4);
    }
    __syncthreads();

    if (lane < TT) {
        int M = lane;
        for (int ii = cnt - 1; ii >= 0; --ii) M = lbp[ii * TT + M];
        G[(b * NSEG + s) * TT + lane] = (unsigned char)M;
    }
}

// ---------------------------------------------------------------------------
// K4: chain across segments: boundary tag at each segment start.
__global__ void k_boundary(const unsigned char* __restrict__ G,
                           unsigned char* __restrict__ bound) {
    int b = threadIdx.x;                 // 128 threads, 1 block
    int x = bound[b * (NSEG + 1) + NSEG];
    for (int s = NSEG - 1; s >= 0; --s) {
        x = G[(b * NSEG + s) * TT + x];
        bound[b * (NSEG + 1) + s] = x;
    }
}

// ---------------------------------------------------------------------------
// K5: fill tags within each segment by re-walking its bp maps from the known
// entering boundary tag. Writes final float tags.
__global__ __launch_bounds__(64) void k_fill(const char* __restrict__ statesBase,
                                             const unsigned char* __restrict__ bound,
                                             float* __restrict__ tags) {
    const int s = blockIdx.x, b = blockIdx.y;
    const int i0 = s * SEG;
    const int cnt = (SEG < NBP - i0) ? SEG : (NBP - i0);
    const int lane = threadIdx.x;

    __shared__ unsigned char lbp[SEG * TT];
    const char* sb = statesBase + (size_t)b * NBP * SLOT;
    for (int ii = 0; ii < cnt; ++ii) {
        if (lane < 12)
            ((uint32_t*)lbp)[ii * 12 + lane] =
                *(const uint32_t*)(sb + (size_t)(i0 + ii) * SLOT + (size_t)lane * 4);
    }
    __syncthreads();

    if (lane == 0) {
        int x = bound[b * (NSEG + 1) + s + 1];   // tag at position (s+1)*SEG (or last_tag)
        if (s == NSEG - 1)
            tags[(size_t)b * NPOT + (NPOT - 1)] = (float)x;
        for (int ii = cnt - 1; ii >= 0; --ii) {
            x = lbp[ii * TT + x];
            tags[(size_t)b * NPOT + i0 + ii] = (float)x;
        }
    }
}

// ---------------------------------------------------------------------------
// K6: final copies — pot = in[:,1:-1,:] and transitions passthrough.
__global__ __launch_bounds__(256) void k_copy(const float* __restrict__ in,
                                              const float* __restrict__ trans,
                                              float* __restrict__ out) {
    const int potN4 = (BATCH * NPOT * TT) / 4;   // 6,288,384 float4s
    const int rowN = NPOT * TT;                  // 196,512
    int idx = blockIdx.x * 256 + threadIdx.x;
    if (idx < potN4) {
        int p4 = idx * 4;
        int b = p4 / rowN;
        int off = p4 - b * rowN;
        float4 v = *(const float4*)(in + (size_t)b * (LFULL * TT) + off + TT);
        *(float4*)(out + p4) = v;
    } else if (idx < potN4 + (TT * TT) / 4) {
        int q = idx - potN4;
        *(float4*)(out + (size_t)BATCH * NPOT * TT + (size_t)q * 4) =
            *(const float4*)(trans + (size_t)q * 4);
    }
}

// ---------------------------------------------------------------------------
extern "C" void kernel_launch(void* const* d_in, const int* in_sizes, int n_in,
                              void* d_out, int out_size, void* d_ws, size_t ws_size,
                              hipStream_t stream) {
    (void)in_sizes; (void)n_in; (void)d_ws; (void)ws_size; (void)out_size;

    const float* in = (const float*)d_in[0];
    const float* trans = (const float*)d_in[1];
    float* out = (float*)d_out;

    // Scratch carved out of d_out (stream-ordered so everything is rewritten):
    //  - pot region   [0 .. 100.6MB): state vectors, then bp bytes in-place
    //  - trans region [2304 floats]: boundary tags (128 x 65 bytes)
    //  - tags region  [524032 floats]: segment maps G, then final tags
    char* statesBase = (char*)d_out;
    unsigned char* bound = (unsigned char*)(out + (size_t)BATCH * NPOT * TT);
    unsigned char* G = (unsigned char*)(out + (size_t)BATCH * NPOT * TT + TT * TT);
    float* tags = out + (size_t)BATCH * NPOT * TT + TT * TT;

    k_forward <<<dim3(BATCH),        dim3(64),  0, stream>>>(in, trans, statesBase, bound);
    k_bp      <<<dim3(256, 32),      dim3(256), 0, stream>>>(trans, statesBase);
    k_compose <<<dim3(NSEG, BATCH),  dim3(64),  0, stream>>>(statesBase, G);
    k_boundary<<<dim3(1),            dim3(BATCH), 0, stream>>>(G, bound);
    k_fill    <<<dim3(NSEG, BATCH),  dim3(64),  0, stream>>>(statesBase, bound, tags);

    int total4 = (BATCH * NPOT * TT) / 4 + (TT * TT) / 4;
    k_copy    <<<dim3((total4 + 255) / 256), dim3(256), 0, stream>>>(in, trans, out);
}